// Round 1
// baseline (738.848 us; speedup 1.0000x reference)
//
#include <hip/hip_runtime.h>
#include <hip/hip_bf16.h>

// GAT layer, N=8192, D_IN=512, D_OUT=128.
// Key identity: softmax row-max cancels a1[i]; attention = adj*e^{a2[j]} / sum_j adj*e^{a2[j]}.
// Pipeline:
//   k_fc : h = x @ W_fc                      (fp32 vector GEMM, LDS-tiled)
//   k_a2 : a2[j] = h[j] . w_a2               (wave-per-row-batch reduce)
//   k_gt : G^T[144][8192] bf16, rows 0..127 = e[j]*h[j][d], row 128 = e[j], 129..143 = 0
//   k_gat: [num|den] = adj @ G via MFMA bf16; out = num/den   (memory-bound on adj stream)

#define NN 8192
#define DIN 512
#define DOUT 128
#define NT 144   // 128 + 16 (den column tile)

typedef __attribute__((ext_vector_type(4))) int   int4v;
typedef __attribute__((ext_vector_type(4))) float f32x4;
typedef __attribute__((ext_vector_type(8))) short bf16x8;

static __device__ __forceinline__ unsigned short f2bf(float f) {
    unsigned u = __float_as_uint(f);
    unsigned r = (u + 0x7FFFu + ((u >> 16) & 1u)) >> 16;
    return (unsigned short)r;
}

// ---------------- k_fc: h = x @ W_fc (fp32), BM=32, BK=32, 256 thr ----------------
__global__ __launch_bounds__(256) void k_fc(const float* __restrict__ x,
                                            const float* __restrict__ W,
                                            float* __restrict__ h) {
    __shared__ float xs[32][36];   // pad to 36 floats
    __shared__ float ws_[32][128];
    const int t  = threadIdx.x;
    const int tx = t & 31;         // col group: 4 cols each
    const int ty = t >> 5;         // row group: 4 rows each
    const int m0 = blockIdx.x * 32;

    float acc[4][4] = {};
    for (int kb = 0; kb < DIN; kb += 32) {
        {   // stage x tile: 32 rows x 32 k = 256 float4, 1/thread
            int r  = t >> 3;
            int c4 = (t & 7) * 4;
            float4 v = *reinterpret_cast<const float4*>(&x[(size_t)(m0 + r) * DIN + kb + c4]);
            *reinterpret_cast<float4*>(&xs[r][c4]) = v;
        }
        #pragma unroll
        for (int i = 0; i < 4; ++i) {   // stage W tile: 32 x 128 = 1024 float4, 4/thread
            int f4 = t + i * 256;
            int r  = f4 >> 5;
            int c4 = (f4 & 31) * 4;
            float4 v = *reinterpret_cast<const float4*>(&W[(size_t)(kb + r) * DOUT + c4]);
            *reinterpret_cast<float4*>(&ws_[r][c4]) = v;
        }
        __syncthreads();
        #pragma unroll
        for (int kk = 0; kk < 32; ++kk) {
            float4 wv = *reinterpret_cast<const float4*>(&ws_[kk][tx * 4]);
            #pragma unroll
            for (int i = 0; i < 4; ++i) {
                float xv = xs[ty * 4 + i][kk];
                acc[i][0] += xv * wv.x; acc[i][1] += xv * wv.y;
                acc[i][2] += xv * wv.z; acc[i][3] += xv * wv.w;
            }
        }
        __syncthreads();
    }
    #pragma unroll
    for (int i = 0; i < 4; ++i) {
        float4 v = {acc[i][0], acc[i][1], acc[i][2], acc[i][3]};
        *reinterpret_cast<float4*>(&h[(size_t)(m0 + ty * 4 + i) * DOUT + tx * 4]) = v;
    }
}

// ---------------- k_a2: a2[j] = h[j] . w_a2 ----------------
__global__ __launch_bounds__(256) void k_a2(const float* __restrict__ h,
                                            const float* __restrict__ wa2,
                                            float* __restrict__ a2) {
    const int wid  = blockIdx.x * 4 + (threadIdx.x >> 6);  // 256 waves
    const int lane = threadIdx.x & 63;
    float2 wv = *reinterpret_cast<const float2*>(&wa2[lane * 2]);
    for (int rr = 0; rr < 32; ++rr) {
        int j = wid * 32 + rr;
        float2 hv = *reinterpret_cast<const float2*>(&h[(size_t)j * DOUT + lane * 2]);
        float v = hv.x * wv.x + hv.y * wv.y;
        #pragma unroll
        for (int off = 32; off; off >>= 1) v += __shfl_down(v, off);
        if (lane == 0) a2[j] = v;
    }
}

// ---------------- k_gt: build G^T [NT][NN] bf16 ----------------
// block: 64 j-rows x 128 d-cols, LDS transpose
__global__ __launch_bounds__(256) void k_gt(const float* __restrict__ h,
                                            const float* __restrict__ a2,
                                            unsigned short* __restrict__ Gt) {
    __shared__ float tile[64][133];
    __shared__ float es[64];
    const int t  = threadIdx.x;
    const int j0 = blockIdx.x * 64;

    #pragma unroll
    for (int i = 0; i < 8; ++i) {   // 64x128 floats = 2048 float4, 8/thread
        int f4 = t + i * 256;
        int r  = f4 >> 5;
        int c4 = (f4 & 31) * 4;
        float4 v = *reinterpret_cast<const float4*>(&h[(size_t)(j0 + r) * DOUT + c4]);
        tile[r][c4] = v.x; tile[r][c4 + 1] = v.y; tile[r][c4 + 2] = v.z; tile[r][c4 + 3] = v.w;
    }
    if (t < 64) es[t] = expf(a2[j0 + t]);
    __syncthreads();

    const int d  = t >> 1;
    const int jh = (t & 1) * 32;
    unsigned o[16];
    #pragma unroll
    for (int p = 0; p < 16; ++p) {
        int j1 = jh + p * 2, j2 = j1 + 1;
        float v1 = tile[j1][d] * es[j1];
        float v2 = tile[j2][d] * es[j2];
        o[p] = (unsigned)f2bf(v1) | ((unsigned)f2bf(v2) << 16);
    }
    uint4* dst = reinterpret_cast<uint4*>(&Gt[(size_t)d * NN + j0 + jh]);
    const uint4* src = reinterpret_cast<const uint4*>(o);
    dst[0] = src[0]; dst[1] = src[1]; dst[2] = src[2]; dst[3] = src[3];

    // row 128 = e[j] (bf16); rows 129..143 = 0
    if (t < 32) {
        unsigned u = (unsigned)f2bf(es[t * 2]) | ((unsigned)f2bf(es[t * 2 + 1]) << 16);
        reinterpret_cast<unsigned*>(&Gt[(size_t)128 * NN + j0])[t] = u;
    }
    for (int z = t; z < 15 * 32; z += 256) {
        int zr = z >> 5, zc = z & 31;
        reinterpret_cast<unsigned*>(&Gt[(size_t)(129 + zr) * NN + j0])[zc] = 0u;
    }
}

// ---------------- k_gat: [num|den] = adj @ G, out = num/den ----------------
// wave owns 16 rows x all 144 cols; adj nt-streamed, B-frags from L2; no main-loop barriers.
static __device__ __forceinline__ int4v ntld(const int* p) {
    return __builtin_nontemporal_load(reinterpret_cast<const int4v*>(p));
}
static __device__ __forceinline__ bf16x8 adj2bf(int4v a, int4v b) {
    unsigned u0 = (unsigned)a.x * 0x3F80u | (((unsigned)a.y * 0x3F80u) << 16);
    unsigned u1 = (unsigned)a.z * 0x3F80u | (((unsigned)a.w * 0x3F80u) << 16);
    unsigned u2 = (unsigned)b.x * 0x3F80u | (((unsigned)b.y * 0x3F80u) << 16);
    unsigned u3 = (unsigned)b.z * 0x3F80u | (((unsigned)b.w * 0x3F80u) << 16);
    int4v p = {(int)u0, (int)u1, (int)u2, (int)u3};
    return __builtin_bit_cast(bf16x8, p);
}

__global__ __launch_bounds__(128) void k_gat(const int* __restrict__ adj,
                                             const unsigned short* __restrict__ Gt,
                                             float* __restrict__ out) {
    const int t    = threadIdx.x;
    const int widx = t >> 6;
    const int l    = t & 63;
    const int wgid = blockIdx.x * 2 + widx;
    const int row0 = wgid * 16;
    const int m    = l & 15;   // A row / B col within tile
    const int kq   = l >> 4;   // k-quarter (8 elems)
    __shared__ float den_lds[2][16];

    f32x4 acc[9];
    #pragma unroll
    for (int i = 0; i < 9; ++i) acc[i] = (f32x4)0.f;

    const int* arow = adj + (size_t)(row0 + m) * NN + kq * 8;

    int4v ra0 = ntld(arow + 0);
    int4v ra1 = ntld(arow + 4);
    int4v rb0 = ntld(arow + 32);
    int4v rb1 = ntld(arow + 36);

    for (int kt = 0; kt < NN; kt += 64) {
        bf16x8 a0 = adj2bf(ra0, ra1);
        bf16x8 a1 = adj2bf(rb0, rb1);
        if (kt < NN - 64) {
            const int* nx = arow + kt + 64;
            ra0 = ntld(nx + 0);
            ra1 = ntld(nx + 4);
            rb0 = ntld(nx + 32);
            rb1 = ntld(nx + 36);
        }
        #pragma unroll
        for (int ct = 0; ct < 9; ++ct) {
            const unsigned short* gp = Gt + (size_t)(ct * 16 + m) * NN + kt + kq * 8;
            bf16x8 b0 = *reinterpret_cast<const bf16x8*>(gp);
            bf16x8 b1 = *reinterpret_cast<const bf16x8*>(gp + 32);
            acc[ct] = __builtin_amdgcn_mfma_f32_16x16x32_bf16(a0, b0, acc[ct], 0, 0, 0);
            acc[ct] = __builtin_amdgcn_mfma_f32_16x16x32_bf16(a1, b1, acc[ct], 0, 0, 0);
        }
    }

    // den sits in acc[8] lanes with m==0 (col 128), rows kq*4+r
    if (m == 0) {
        #pragma unroll
        for (int r = 0; r < 4; ++r) den_lds[widx][kq * 4 + r] = acc[8][r];
    }
    __syncthreads();

    #pragma unroll
    for (int r = 0; r < 4; ++r) {
        int mr = kq * 4 + r;
        float inv = 1.0f / den_lds[widx][mr];
        float* orow = out + (size_t)(row0 + mr) * DOUT + m;
        #pragma unroll
        for (int ct = 0; ct < 8; ++ct) orow[ct * 16] = acc[ct][r] * inv;
    }
}

extern "C" void kernel_launch(void* const* d_in, const int* in_sizes, int n_in,
                              void* d_out, int out_size, void* d_ws, size_t ws_size,
                              hipStream_t stream) {
    const float* x   = (const float*)d_in[0];
    const int*   adj = (const int*)d_in[1];
    const float* W   = (const float*)d_in[2];
    // d_in[3] = w_a1: unused — cancels in row softmax.
    const float* wa2 = (const float*)d_in[4];
    float* out = (float*)d_out;

    char* ws = (char*)d_ws;
    float*          h   = (float*)ws;                               // 4 MB
    float*          a2  = (float*)(ws + (size_t)NN * DOUT * 4);     // 32 KB
    unsigned short* Gt  = (unsigned short*)(ws + 4 * 1024 * 1024 + 64 * 1024); // 2.36 MB

    k_fc <<<256, 256, 0, stream>>>(x, W, h);
    k_a2 <<< 64, 256, 0, stream>>>(h, wa2, a2);
    k_gt <<<128, 256, 0, stream>>>(h, a2, Gt);
    k_gat<<<256, 128, 0, stream>>>(adj, Gt, out);
}

// Round 2
// 544.213 us; speedup vs baseline: 1.3576x; 1.3576x over previous
//
#include <hip/hip_runtime.h>
#include <hip/hip_bf16.h>

// GAT layer, N=8192, D_IN=512, D_OUT=128.
// Identity: softmax row-max cancels a1[i]; attention = adj*e^{a2[j]} / sum_j adj*e^{a2[j]}.
// Pipeline:
//   k_fc : h = x @ W_fc                    (fp32 vector, BM=8, 1024 blocks)
//   k_gt : e = exp(h.w_a2) fused; G^T[144][8192] bf16: rows 0..127 = e[j]*h[j][d],
//          row 128 = e[j], 129..143 = 0    (512 blocks)
//   k_gat: [num|den] = adj @ G via MFMA bf16, split-K x8 in-block + LDS tree reduce;
//          out = num/den                   (512 blocks x 512 thr, 16 waves/CU)

#define NN 8192
#define DIN 512
#define DOUT 128

typedef __attribute__((ext_vector_type(4))) int   int4v;
typedef __attribute__((ext_vector_type(4))) float f32x4;
typedef __attribute__((ext_vector_type(8))) short bf16x8;

static __device__ __forceinline__ unsigned short f2bf(float f) {
    unsigned u = __float_as_uint(f);
    unsigned r = (u + 0x7FFFu + ((u >> 16) & 1u)) >> 16;
    return (unsigned short)r;
}

// ---------------- k_fc: h = x @ W_fc (fp32). BM=8, grid 1024, 256 thr ----------------
__global__ __launch_bounds__(256) void k_fc(const float* __restrict__ x,
                                            const float* __restrict__ W,
                                            float* __restrict__ h) {
    __shared__ float xs[8][DIN];   // 16 KB
    const int t  = threadIdx.x;
    const int m0 = blockIdx.x * 8;

    #pragma unroll
    for (int i = 0; i < 4; ++i) {   // 8x512 fp32 = 1024 float4, 4/thread
        int idx = t + i * 256;
        int r   = idx >> 7;          // 128 float4 per row
        int c4  = (idx & 127) * 4;
        float4 v = *reinterpret_cast<const float4*>(&x[(size_t)(m0 + r) * DIN + c4]);
        *reinterpret_cast<float4*>(&xs[r][c4]) = v;
    }
    __syncthreads();

    const int r = t >> 5;          // 8 rows
    const int c = (t & 31) * 4;    // 32 col-groups
    float4 acc = {0.f, 0.f, 0.f, 0.f};
    #pragma unroll 8
    for (int k = 0; k < DIN; ++k) {
        float4 wv = *reinterpret_cast<const float4*>(&W[(size_t)k * DOUT + c]);
        float  xv = xs[r][k];
        acc.x += xv * wv.x; acc.y += xv * wv.y;
        acc.z += xv * wv.z; acc.w += xv * wv.w;
    }
    *reinterpret_cast<float4*>(&h[(size_t)(m0 + r) * DOUT + c]) = acc;
}

// ---------------- k_gt: build G^T [144][NN] bf16, e fused ----------------
__global__ __launch_bounds__(256) void k_gt(const float* __restrict__ h,
                                            const float* __restrict__ wa2,
                                            unsigned short* __restrict__ Gt) {
    __shared__ float tile[16][132];
    __shared__ float wl[DOUT];
    __shared__ float es[16];
    const int t  = threadIdx.x;
    const int j0 = blockIdx.x * 16;

    #pragma unroll
    for (int i = 0; i < 2; ++i) {   // 16x128 fp32 = 512 float4, 2/thread
        int idx = t + i * 256;
        int r   = idx >> 5;
        int c4  = (idx & 31) * 4;
        float4 v = *reinterpret_cast<const float4*>(&h[(size_t)(j0 + r) * DOUT + c4]);
        *reinterpret_cast<float4*>(&tile[r][c4]) = v;
    }
    if (t < DOUT) wl[t] = wa2[t];
    __syncthreads();

    {   // e[j] = exp(h[j].wa2): j = t>>4, 16 lanes x 8 elems each
        const int j = t >> 4;
        const int q = t & 15;
        float s = 0.f;
        #pragma unroll
        for (int kk = 0; kk < 8; ++kk) s += tile[j][q * 8 + kk] * wl[q * 8 + kk];
        s += __shfl_xor(s, 1); s += __shfl_xor(s, 2);
        s += __shfl_xor(s, 4); s += __shfl_xor(s, 8);
        if (q == 0) es[j] = expf(s);
    }
    __syncthreads();

    {   // transpose-write: d = t>>1 (128), jh = (t&1)*8
        const int d  = t >> 1;
        const int jh = (t & 1) * 8;
        unsigned o[4];
        #pragma unroll
        for (int p = 0; p < 4; ++p) {
            int j1 = jh + p * 2, j2 = j1 + 1;
            o[p] = (unsigned)f2bf(tile[j1][d] * es[j1]) |
                   ((unsigned)f2bf(tile[j2][d] * es[j2]) << 16);
        }
        *reinterpret_cast<uint4*>(&Gt[(size_t)d * NN + j0 + jh]) =
            *reinterpret_cast<const uint4*>(o);
    }
    // row 128 = e[j]; rows 129..143 = 0
    if (t < 8) {
        unsigned u = (unsigned)f2bf(es[t * 2]) | ((unsigned)f2bf(es[t * 2 + 1]) << 16);
        reinterpret_cast<unsigned*>(&Gt[(size_t)128 * NN + j0])[t] = u;
    }
    if (t < 120) {
        int zr = t >> 3, zc = t & 7;
        reinterpret_cast<unsigned*>(&Gt[(size_t)(129 + zr) * NN + j0])[zc] = 0u;
    }
}

// ---------------- k_gat: [num|den] = adj @ G, split-K x8, out = num/den ----------------
static __device__ __forceinline__ int4v ntld(const int* p) {
    return __builtin_nontemporal_load(reinterpret_cast<const int4v*>(p));
}
static __device__ __forceinline__ bf16x8 adj2bf(int4v a, int4v b) {
    unsigned u0 = (unsigned)a.x * 0x3F80u | (((unsigned)a.y * 0x3F80u) << 16);
    unsigned u1 = (unsigned)a.z * 0x3F80u | (((unsigned)a.w * 0x3F80u) << 16);
    unsigned u2 = (unsigned)b.x * 0x3F80u | (((unsigned)b.y * 0x3F80u) << 16);
    unsigned u3 = (unsigned)b.z * 0x3F80u | (((unsigned)b.w * 0x3F80u) << 16);
    int4v p = {(int)u0, (int)u1, (int)u2, (int)u3};
    return __builtin_bit_cast(bf16x8, p);
}

__global__ __launch_bounds__(512, 4) void k_gat(const int* __restrict__ adj,
                                                const unsigned short* __restrict__ Gt,
                                                float* __restrict__ out) {
    __shared__ float red[4][64][37];   // 37 KB tree-reduce buffer (pad 37: conflict-free)
    const int t    = threadIdx.x;
    const int widx = t >> 6;           // 8 waves: split-K
    const int l    = t & 63;
    const int row0 = blockIdx.x * 16;
    const int m    = l & 15;           // A row / B col within 16x16 tile
    const int kq   = l >> 4;           // k-quarter (8 elems)
    const int kbase = widx * 1024;     // this wave's K-chunk

    f32x4 acc[9];
    #pragma unroll
    for (int i = 0; i < 9; ++i) acc[i] = (f32x4)0.f;

    const int* arow = adj + (size_t)(row0 + m) * NN + kbase + kq * 8;

    // depth-2 adj prefetch, statically indexed (full unroll keeps regs, not scratch)
    int4v pa[2][4];
    #pragma unroll
    for (int d = 0; d < 2; ++d) {
        const int* p = arow + d * 64;
        pa[d][0] = ntld(p);      pa[d][1] = ntld(p + 4);
        pa[d][2] = ntld(p + 32); pa[d][3] = ntld(p + 36);
    }

    #pragma unroll
    for (int i = 0; i < 16; ++i) {     // 16 k-tiles of 64
        const int cur = i & 1;
        bf16x8 a0 = adj2bf(pa[cur][0], pa[cur][1]);
        bf16x8 a1 = adj2bf(pa[cur][2], pa[cur][3]);
        if (i < 14) {
            const int* p = arow + (i + 2) * 64;
            pa[cur][0] = ntld(p);      pa[cur][1] = ntld(p + 4);
            pa[cur][2] = ntld(p + 32); pa[cur][3] = ntld(p + 36);
        }
        const int kt = kbase + i * 64;
        #pragma unroll
        for (int ct = 0; ct < 9; ++ct) {
            const unsigned short* gp = Gt + (size_t)(ct * 16 + m) * NN + kt + kq * 8;
            bf16x8 b0 = *reinterpret_cast<const bf16x8*>(gp);
            bf16x8 b1 = *reinterpret_cast<const bf16x8*>(gp + 32);
            acc[ct] = __builtin_amdgcn_mfma_f32_16x16x32_bf16(a0, b0, acc[ct], 0, 0, 0);
            acc[ct] = __builtin_amdgcn_mfma_f32_16x16x32_bf16(a1, b1, acc[ct], 0, 0, 0);
        }
    }

    // ---- tree reduction across the 8 K-split waves ----
    // round 1: waves 4..7 -> red[0..3]; waves 0..3 add
    if (widx >= 4) {
        float* dst = &red[widx - 4][l][0];
        #pragma unroll
        for (int ct = 0; ct < 9; ++ct)
            #pragma unroll
            for (int r = 0; r < 4; ++r) dst[ct * 4 + r] = acc[ct][r];
    }
    __syncthreads();
    if (widx < 4) {
        const float* src = &red[widx][l][0];
        #pragma unroll
        for (int ct = 0; ct < 9; ++ct)
            #pragma unroll
            for (int r = 0; r < 4; ++r) acc[ct][r] += src[ct * 4 + r];
    }
    __syncthreads();
    // round 2: waves 2,3 -> red[0,1]; waves 0,1 add
    if (widx == 2 || widx == 3) {
        float* dst = &red[widx - 2][l][0];
        #pragma unroll
        for (int ct = 0; ct < 9; ++ct)
            #pragma unroll
            for (int r = 0; r < 4; ++r) dst[ct * 4 + r] = acc[ct][r];
    }
    __syncthreads();
    if (widx < 2) {
        const float* src = &red[widx][l][0];
        #pragma unroll
        for (int ct = 0; ct < 9; ++ct)
            #pragma unroll
            for (int r = 0; r < 4; ++r) acc[ct][r] += src[ct * 4 + r];
    }
    __syncthreads();
    // round 3: wave 1 -> red[0]; wave 0 adds + epilogue
    if (widx == 1) {
        float* dst = &red[0][l][0];
        #pragma unroll
        for (int ct = 0; ct < 9; ++ct)
            #pragma unroll
            for (int r = 0; r < 4; ++r) dst[ct * 4 + r] = acc[ct][r];
    }
    __syncthreads();
    if (widx == 0) {
        const float* src = &red[0][l][0];
        #pragma unroll
        for (int ct = 0; ct < 9; ++ct)
            #pragma unroll
            for (int r = 0; r < 4; ++r) acc[ct][r] += src[ct * 4 + r];

        // den for row kq*4+r lives in acc[8][r] of lane kq*16 (m==0) — same kq group
        #pragma unroll
        for (int r = 0; r < 4; ++r) {
            float den = __shfl(acc[8][r], l & 48);
            float inv = 1.0f / den;
            int   mr  = kq * 4 + r;
            float* orow = out + (size_t)(row0 + mr) * DOUT + m;
            #pragma unroll
            for (int ct = 0; ct < 8; ++ct) orow[ct * 16] = acc[ct][r] * inv;
        }
    }
}

extern "C" void kernel_launch(void* const* d_in, const int* in_sizes, int n_in,
                              void* d_out, int out_size, void* d_ws, size_t ws_size,
                              hipStream_t stream) {
    const float* x   = (const float*)d_in[0];
    const int*   adj = (const int*)d_in[1];
    const float* W   = (const float*)d_in[2];
    // d_in[3] = w_a1: unused — cancels in row softmax.
    const float* wa2 = (const float*)d_in[4];
    float* out = (float*)d_out;

    char* ws = (char*)d_ws;
    float*          h  = (float*)ws;                               // 4 MB
    unsigned short* Gt = (unsigned short*)(ws + 4 * 1024 * 1024);  // 2.36 MB

    k_fc <<<1024, 256, 0, stream>>>(x, W, h);
    k_gt <<< 512, 256, 0, stream>>>(h, wa2, Gt);
    k_gat<<< 512, 512, 0, stream>>>(adj, Gt, out);
}